// Round 1
// baseline (2213.485 us; speedup 1.0000x reference)
//
#include <hip/hip_runtime.h>
#include <hip/hip_bf16.h>

#define S_ 577
#define B_ 16
#define H_ 16
#define DH 64
#define DM 1024
#define BH_ 256
#define DT_ 0.01f
#define BETA_ 4.0f
#define SCALE_ 0.125f

// ---------------------------------------------------------------------------
// K1: per-(b,h) projections: q,k,v = xh@W + b ; omega/theta ; z0 = (cos,sin)
// ---------------------------------------------------------------------------
__global__ __launch_bounds__(512) void k_proj(
    const float* __restrict__ x,
    const float* __restrict__ Wq, const float* __restrict__ bq,
    const float* __restrict__ Wk, const float* __restrict__ bk,
    const float* __restrict__ Wv, const float* __restrict__ bv,
    const float* __restrict__ Wom, const float* __restrict__ bom,
    const float* __restrict__ Wth, const float* __restrict__ bth,
    float* __restrict__ q, float* __restrict__ k, float* __restrict__ v,
    float* __restrict__ om, float* __restrict__ zp)
{
    __shared__ __align__(16) float Wq_l[4096], Wk_l[4096], Wv_l[4096];
    __shared__ float Wom_l[64], Wth_l[64];
    int bh = blockIdx.x, b = bh >> 4, h = bh & 15;
    int tid = threadIdx.x;
    for (int i = tid; i < 4096; i += 512) {
        Wq_l[i] = Wq[(size_t)h*4096 + i];
        Wk_l[i] = Wk[(size_t)h*4096 + i];
        Wv_l[i] = Wv[(size_t)h*4096 + i];
    }
    if (tid < 64) { Wom_l[tid] = Wom[h*64 + tid]; Wth_l[tid] = Wth[h*64 + tid]; }
    __syncthreads();
    int wid = tid >> 6, lane = tid & 63;
    float bqv = bq[h*64 + lane], bkv = bk[h*64 + lane], bvv = bv[h*64 + lane];
    float bomv = bom[h], bthv = bth[h];
    // 4 rows per wave iteration to amortize W LDS reads
    for (int sb = wid*4; sb < S_; sb += 32) {
        float xr[4]; bool ok[4];
        #pragma unroll
        for (int r = 0; r < 4; ++r) {
            int s = sb + r; ok[r] = (s < S_);
            float xv = 0.f;
            if (ok[r]) xv = x[(size_t)b*S_*DM + (size_t)s*DM + h*DH + lane];
            if (!isfinite(xv)) xv = 0.f;   // nan_to_num
            xr[r] = xv;
        }
        float qa[4] = {0,0,0,0}, ka[4] = {0,0,0,0}, va[4] = {0,0,0,0};
        #pragma unroll 8
        for (int d = 0; d < 64; ++d) {
            float wq = Wq_l[d*64 + lane], wk = Wk_l[d*64 + lane], wv = Wv_l[d*64 + lane];
            #pragma unroll
            for (int r = 0; r < 4; ++r) {
                float xd = __shfl(xr[r], d, 64);
                qa[r] = fmaf(xd, wq, qa[r]);
                ka[r] = fmaf(xd, wk, ka[r]);
                va[r] = fmaf(xd, wv, va[r]);
            }
        }
        #pragma unroll
        for (int r = 0; r < 4; ++r) {
            float omp = xr[r] * Wom_l[lane], thp = xr[r] * Wth_l[lane];
            #pragma unroll
            for (int m = 32; m; m >>= 1) {
                omp += __shfl_xor(omp, m, 64);
                thp += __shfl_xor(thp, m, 64);
            }
            if (ok[r]) {
                int s = sb + r;
                size_t base = (size_t)bh*S_*DH + (size_t)s*DH + lane;
                q[base] = qa[r] + bqv;
                k[base] = ka[r] + bkv;
                v[base] = va[r] + bvv;
                if (lane == 0) {
                    float oms = omp + bomv, th = thp + bthv;
                    om[(size_t)bh*S_ + s] = oms;
                    float si, co;
                    sincosf(th, &si, &co);
                    reinterpret_cast<float2*>(zp)[(size_t)bh*S_ + s] = make_float2(co, si);
                }
            }
        }
    }
}

// ---------------------------------------------------------------------------
// K2: Stuart-Landau ODE, 10 Heun steps. Kc@z factored as c*q@(k^T z).
// k resident in LDS (147.7KB); z, z1 in LDS; q streamed from L2.
// ---------------------------------------------------------------------------
__global__ __launch_bounds__(512) void k_ode(
    const float* __restrict__ q, const float* __restrict__ k,
    const float* __restrict__ om,
    const float* __restrict__ mu, const float* __restrict__ kappa,
    const float* __restrict__ alpha, const int* __restrict__ nsim,
    float* __restrict__ zp)
{
    __shared__ __align__(16) float k_l[S_*DH];       // 147712 B
    __shared__ float2 z_l[S_], z1_l[S_];             // 2 x 4616 B
    __shared__ float2 kz_s[8][64];                   // 4096 B
    int bh = blockIdx.x, h = bh & 15;
    int tid = threadIdx.x;
    const float* kg = k + (size_t)bh*S_*DH;
    {
        const float4* kg4 = reinterpret_cast<const float4*>(kg);
        float4* kl4 = reinterpret_cast<float4*>(k_l);
        for (int i = tid; i < S_*DH/4; i += 512) kl4[i] = kg4[i];
    }
    float2* zpg = reinterpret_cast<float2*>(zp) + (size_t)bh*S_;
    for (int i = tid; i < S_; i += 512) z_l[i] = zpg[i];
    float ca = cosf(alpha[h]), sa = sinf(alpha[h]);
    float muv = mu[h];
    float cc = kappa[h] * SCALE_ / (float)S_;
    int NT = nsim[0];
    __syncthreads();
    int wid = tid >> 6, lane = tid & 63;
    int s0 = wid * 73, s1 = min(S_, s0 + 73);
    int i8 = lane >> 3, d0 = (lane & 7) << 3;
    const float* qg = q + (size_t)bh*S_*DH;
    const float* omg = om + (size_t)bh*S_;
    for (int ev = 0; ev < 2*NT; ++ev) {
        bool second = ev & 1;
        const float2* zin = second ? z1_l : z_l;
        // phase A: partial kz[e] = sum_s k[s][e] * z[s]
        float accr = 0.f, acci = 0.f;
        for (int s = s0; s < s1; ++s) {
            float kv = k_l[s*64 + lane];
            float2 z = zin[s];
            accr = fmaf(kv, z.x, accr);
            acci = fmaf(kv, z.y, acci);
        }
        kz_s[wid][lane] = make_float2(accr, acci);
        __syncthreads();
        if (tid < 64) {
            float2 t = kz_s[0][lane];
            #pragma unroll
            for (int w = 1; w < 8; ++w) { float2 u = kz_s[w][lane]; t.x += u.x; t.y += u.y; }
            kz_s[0][lane] = t;
        }
        __syncthreads();
        float kzr[8], kzi[8];
        #pragma unroll
        for (int j = 0; j < 8; ++j) { float2 t = kz_s[0][d0 + j]; kzr[j] = t.x; kzi[j] = t.y; }
        // phase B: u_s = c * q_s . kz ; pointwise Stuart-Landau + Heun update
        for (int sb = s0; sb < s1; sb += 8) {
            int s = sb + i8;
            bool act = (s < s1);
            float ur = 0.f, ui = 0.f;
            if (act) {
                const float4* q4 = reinterpret_cast<const float4*>(qg + (size_t)s*DH + d0);
                float4 qa = q4[0], qb = q4[1];
                ur = fmaf(qa.x,kzr[0],fmaf(qa.y,kzr[1],fmaf(qa.z,kzr[2],fmaf(qa.w,kzr[3],
                     fmaf(qb.x,kzr[4],fmaf(qb.y,kzr[5],fmaf(qb.z,kzr[6],qb.w*kzr[7])))))));
                ui = fmaf(qa.x,kzi[0],fmaf(qa.y,kzi[1],fmaf(qa.z,kzi[2],fmaf(qa.w,kzi[3],
                     fmaf(qb.x,kzi[4],fmaf(qb.y,kzi[5],fmaf(qb.z,kzi[6],qb.w*kzi[7])))))));
            }
            #pragma unroll
            for (int m = 1; m < 8; m <<= 1) {
                ur += __shfl_xor(ur, m, 64);
                ui += __shfl_xor(ui, m, 64);
            }
            if (act) {
                float2 z = zin[s];
                float omega_s = omg[s];
                float urc = cc*ur, uic = cc*ui;
                float cr = ca*urc + sa*uic;
                float ci = ca*uic - sa*urc;
                float g = muv - (z.x*z.x + z.y*z.y);
                float dr = fmaf(g, z.x, fmaf(-omega_s, z.y, cr));
                float di = fmaf(g, z.y, fmaf( omega_s, z.x, ci));
                if (d0 == 0) {
                    float2 zb = z_l[s];
                    if (!second) {
                        z1_l[s] = make_float2(fmaf(DT_, dr, z.x), fmaf(DT_, di, z.y));
                        z_l[s]  = make_float2(fmaf(0.5f*DT_, dr, zb.x), fmaf(0.5f*DT_, di, zb.y));
                    } else {
                        z_l[s]  = make_float2(fmaf(0.5f*DT_, dr, zb.x), fmaf(0.5f*DT_, di, zb.y));
                    }
                }
            }
        }
        __syncthreads();
    }
    for (int i = tid; i < S_; i += 512) zpg[i] = z_l[i];
}

// ---------------------------------------------------------------------------
// K3: dual flash attention. Per block: (b,h) x 64-row chunk; 10 t-tiles.
// score_van = q.k*scale (softmax), score_res = BETA*(zr_s zr_t + zi_s zi_t).
// Gate factors out of res-PV. 8 waves x 8 rows, 2 rows share k/v tile reads.
// ---------------------------------------------------------------------------
__global__ __launch_bounds__(512) void k_attn(
    const float* __restrict__ q, const float* __restrict__ k,
    const float* __restrict__ v, const float* __restrict__ zp,
    const float* __restrict__ mix_logit, const float* __restrict__ band_logits,
    float* __restrict__ y)
{
    __shared__ __align__(16) float q_l[64*68];   // 17408
    __shared__ __align__(16) float k_t[64*68];   // 17408
    __shared__ __align__(16) float v_t[64*64];   // 16384
    __shared__ float2 zs_l[64];
    __shared__ float2 zt_l[64];
    __shared__ __align__(16) float2 ab[8][2][64]; // 8192
    int blk = blockIdx.x;
    int bh = blk / 10, rc = blk - bh*10;
    int b = bh >> 4, h = bh & 15;
    int r0 = rc * 64;
    int tid = threadIdx.x, wid = tid >> 6, lane = tid & 63;
    const float2* zpg = reinterpret_cast<const float2*>(zp) + (size_t)bh*S_;
    const float* qg = q + (size_t)bh*S_*DH;
    const float* kg = k + (size_t)bh*S_*DH;
    const float* vg = v + (size_t)bh*S_*DH;
    {   // stage q rows + z_s (pre-scaled by BETA)
        int r = tid >> 3, dd = (tid & 7) << 3;
        int ra = r0 + r;
        float4 t0 = make_float4(0,0,0,0), t1 = t0;
        if (ra < S_) {
            const float4* s4 = reinterpret_cast<const float4*>(qg + (size_t)ra*DH + dd);
            t0 = s4[0]; t1 = s4[1];
        }
        float4* d4 = reinterpret_cast<float4*>(&q_l[r*68 + dd]);
        d4[0] = t0; d4[1] = t1;
        if (tid < 64) {
            float2 zz = (r0 + tid < S_) ? zpg[r0 + tid] : make_float2(0.f,0.f);
            zs_l[tid] = make_float2(zz.x*BETA_, zz.y*BETA_);
        }
    }
    float mv[8], mr[8], Zv[8], Zr[8], yv[8], yr[8];
    #pragma unroll
    for (int i = 0; i < 8; ++i) { mv[i]=-1e30f; mr[i]=-1e30f; Zv[i]=0.f; Zr[i]=0.f; yv[i]=0.f; yr[i]=0.f; }
    for (int tt = 0; tt < 10; ++tt) {
        int t0g = tt * 64;
        __syncthreads();
        {   // stage k,v tile + z_t
            int t = tid >> 3, dd = (tid & 7) << 3;
            int ta = t0g + t;
            float4 a0 = make_float4(0,0,0,0), a1 = a0, b0 = a0, b1 = a0;
            if (ta < S_) {
                const float4* ks4 = reinterpret_cast<const float4*>(kg + (size_t)ta*DH + dd);
                a0 = ks4[0]; a1 = ks4[1];
                const float4* vs4 = reinterpret_cast<const float4*>(vg + (size_t)ta*DH + dd);
                b0 = vs4[0]; b1 = vs4[1];
            }
            float4* kd4 = reinterpret_cast<float4*>(&k_t[t*68 + dd]);
            kd4[0] = a0; kd4[1] = a1;
            float4* vd4 = reinterpret_cast<float4*>(&v_t[t*64 + dd]);
            vd4[0] = b0; vd4[1] = b1;
            if (tid < 64) zt_l[tid] = (t0g + tid < S_) ? zpg[t0g + tid] : make_float2(0.f,0.f);
        }
        __syncthreads();
        float2 zt = zt_l[lane];
        bool tval = (t0g + lane) < S_;
        for (int p = 0; p < 4; ++p) {
            int rr0 = wid*8 + 2*p, rr1 = rr0 + 1;
            int ra0 = r0 + rr0;
            if (ra0 >= S_) continue;        // wave-uniform
            int i0 = 2*p, i1 = 2*p + 1;
            float sv0 = 0.f, sv1 = 0.f;
            #pragma unroll
            for (int d = 0; d < 64; d += 4) {
                float4 kd = *reinterpret_cast<const float4*>(&k_t[lane*68 + d]);
                float4 q0 = *reinterpret_cast<const float4*>(&q_l[rr0*68 + d]);
                float4 q1 = *reinterpret_cast<const float4*>(&q_l[rr1*68 + d]);
                sv0 = fmaf(q0.x, kd.x, sv0); sv0 = fmaf(q0.y, kd.y, sv0);
                sv0 = fmaf(q0.z, kd.z, sv0); sv0 = fmaf(q0.w, kd.w, sv0);
                sv1 = fmaf(q1.x, kd.x, sv1); sv1 = fmaf(q1.y, kd.y, sv1);
                sv1 = fmaf(q1.z, kd.z, sv1); sv1 = fmaf(q1.w, kd.w, sv1);
            }
            sv0 *= SCALE_; sv1 *= SCALE_;
            float2 zs0 = zs_l[rr0], zs1 = zs_l[rr1];
            float sr0 = fmaf(zs0.x, zt.x, zs0.y*zt.y);
            float sr1 = fmaf(zs1.x, zt.x, zs1.y*zt.y);
            if (!tval) { sv0 = -1e30f; sv1 = -1e30f; sr0 = -1e30f; sr1 = -1e30f; }
            float a_ = sv0, b2_ = sr0, c_ = sv1, d_ = sr1;
            #pragma unroll
            for (int mm = 32; mm; mm >>= 1) {
                a_  = fmaxf(a_,  __shfl_xor(a_,  mm, 64));
                b2_ = fmaxf(b2_, __shfl_xor(b2_, mm, 64));
                c_  = fmaxf(c_,  __shfl_xor(c_,  mm, 64));
                d_  = fmaxf(d_,  __shfl_xor(d_,  mm, 64));
            }
            float nmv0 = fmaxf(mv[i0], a_),  nmr0 = fmaxf(mr[i0], b2_);
            float nmv1 = fmaxf(mv[i1], c_),  nmr1 = fmaxf(mr[i1], d_);
            float pv0 = __expf(sv0 - nmv0), pr0 = __expf(sr0 - nmr0);
            float pv1 = __expf(sv1 - nmv1), pr1 = __expf(sr1 - nmr1);
            ab[wid][0][lane] = make_float2(pv0, pr0);
            ab[wid][1][lane] = make_float2(pv1, pr1);
            float u0 = pv0, u1 = pr0, u2 = pv1, u3 = pr1;
            #pragma unroll
            for (int mm = 32; mm; mm >>= 1) {
                u0 += __shfl_xor(u0, mm, 64);
                u1 += __shfl_xor(u1, mm, 64);
                u2 += __shfl_xor(u2, mm, 64);
                u3 += __shfl_xor(u3, mm, 64);
            }
            float fv0 = __expf(mv[i0]-nmv0), fr0 = __expf(mr[i0]-nmr0);
            float fv1 = __expf(mv[i1]-nmv1), fr1 = __expf(mr[i1]-nmr1);
            Zv[i0] = fmaf(Zv[i0], fv0, u0); Zr[i0] = fmaf(Zr[i0], fr0, u1);
            Zv[i1] = fmaf(Zv[i1], fv1, u2); Zr[i1] = fmaf(Zr[i1], fr1, u3);
            yv[i0] *= fv0; yr[i0] *= fr0; yv[i1] *= fv1; yr[i1] *= fr1;
            mv[i0] = nmv0; mr[i0] = nmr0; mv[i1] = nmv1; mr[i1] = nmr1;
            float av0=0.f, ar0=0.f, av1=0.f, ar1=0.f;
            #pragma unroll 8
            for (int t2 = 0; t2 < 64; t2 += 2) {
                float4 p0 = *reinterpret_cast<const float4*>(&ab[wid][0][t2]);
                float4 p1 = *reinterpret_cast<const float4*>(&ab[wid][1][t2]);
                float va_ = v_t[t2*64 + lane];
                float vb_ = v_t[(t2+1)*64 + lane];
                av0 = fmaf(p0.x, va_, av0); ar0 = fmaf(p0.y, va_, ar0);
                av0 = fmaf(p0.z, vb_, av0); ar0 = fmaf(p0.w, vb_, ar0);
                av1 = fmaf(p1.x, va_, av1); ar1 = fmaf(p1.y, va_, ar1);
                av1 = fmaf(p1.z, vb_, av1); ar1 = fmaf(p1.w, vb_, ar1);
            }
            yv[i0] += av0; yr[i0] += ar0; yv[i1] += av1; yr[i1] += ar1;
        }
    }
    float mixv = 1.f/(1.f + __expf(-mix_logit[h]));
    float gv   = 1.f/(1.f + __expf(-band_logits[h*4 + (lane >> 4)]));
    #pragma unroll
    for (int i = 0; i < 8; ++i) {
        int ra = r0 + wid*8 + i;
        if (ra < S_) {
            float val = mixv * gv * (yr[i] / Zr[i]) + (1.f - mixv) * (yv[i] / Zv[i]);
            y[(size_t)b*S_*DM + (size_t)ra*DM + h*DH + lane] = val;
        }
    }
}

// ---------------------------------------------------------------------------
// K4: out = y(9232x1024) @ Wo(1024x1024) + bo. fp32 128x128 tile, 8x8 micro.
// ---------------------------------------------------------------------------
__global__ __launch_bounds__(256) void k_gemm(
    const float* __restrict__ A, const float* __restrict__ Bw,
    const float* __restrict__ bias, float* __restrict__ out)
{
    const int M = B_ * S_;   // 9232
    __shared__ __align__(16) float A_l[16][132];
    __shared__ __align__(16) float B_l[16][128];
    int bm = blockIdx.x, bn = blockIdx.y;
    int tid = threadIdx.x;
    int tx = tid & 15, ty = tid >> 4;
    int m0 = bm * 128, n0 = bn * 128;
    float acc[8][8];
    #pragma unroll
    for (int i = 0; i < 8; ++i)
        #pragma unroll
        for (int j = 0; j < 8; ++j) acc[i][j] = 0.f;
    for (int k0 = 0; k0 < 1024; k0 += 16) {
        __syncthreads();
        {   // stage A (transposed) and B
            int m = tid >> 1, ks = (tid & 1) << 3;
            float4 t0 = make_float4(0,0,0,0), t1 = t0;
            if (m0 + m < M) {
                const float4* s4 = reinterpret_cast<const float4*>(A + (size_t)(m0+m)*1024 + k0 + ks);
                t0 = s4[0]; t1 = s4[1];
            }
            A_l[ks+0][m] = t0.x; A_l[ks+1][m] = t0.y; A_l[ks+2][m] = t0.z; A_l[ks+3][m] = t0.w;
            A_l[ks+4][m] = t1.x; A_l[ks+5][m] = t1.y; A_l[ks+6][m] = t1.z; A_l[ks+7][m] = t1.w;
            int kk = tid >> 4, nn = (tid & 15) << 3;
            const float4* b4 = reinterpret_cast<const float4*>(Bw + (size_t)(k0+kk)*1024 + n0 + nn);
            float4 u0 = b4[0], u1 = b4[1];
            float4* d4 = reinterpret_cast<float4*>(&B_l[kk][nn]);
            d4[0] = u0; d4[1] = u1;
        }
        __syncthreads();
        #pragma unroll
        for (int kk = 0; kk < 16; ++kk) {
            float4 a0 = *reinterpret_cast<const float4*>(&A_l[kk][ty*8]);
            float4 a1 = *reinterpret_cast<const float4*>(&A_l[kk][ty*8+4]);
            float4 b0 = *reinterpret_cast<const float4*>(&B_l[kk][tx*8]);
            float4 b1 = *reinterpret_cast<const float4*>(&B_l[kk][tx*8+4]);
            float af[8] = {a0.x,a0.y,a0.z,a0.w,a1.x,a1.y,a1.z,a1.w};
            float bf[8] = {b0.x,b0.y,b0.z,b0.w,b1.x,b1.y,b1.z,b1.w};
            #pragma unroll
            for (int i = 0; i < 8; ++i)
                #pragma unroll
                for (int j = 0; j < 8; ++j)
                    acc[i][j] = fmaf(af[i], bf[j], acc[i][j]);
        }
    }
    #pragma unroll
    for (int i = 0; i < 8; ++i) {
        int m = m0 + ty*8 + i;
        if (m < M) {
            float* dst = out + (size_t)m*1024 + n0 + tx*8;
            #pragma unroll
            for (int j = 0; j < 8; ++j) dst[j] = acc[i][j] + bias[n0 + tx*8 + j];
        }
    }
}

// ---------------------------------------------------------------------------
extern "C" void kernel_launch(void* const* d_in, const int* in_sizes, int n_in,
                              void* d_out, int out_size, void* d_ws, size_t ws_size,
                              hipStream_t stream)
{
    const float* x   = (const float*)d_in[0];
    const float* Wq  = (const float*)d_in[1];
    const float* bq  = (const float*)d_in[2];
    const float* Wk  = (const float*)d_in[3];
    const float* bk  = (const float*)d_in[4];
    const float* Wv  = (const float*)d_in[5];
    const float* bv  = (const float*)d_in[6];
    const float* Wom = (const float*)d_in[7];
    const float* bom = (const float*)d_in[8];
    const float* Wth = (const float*)d_in[9];
    const float* bth = (const float*)d_in[10];
    const float* mu  = (const float*)d_in[11];
    const float* kap = (const float*)d_in[12];
    const float* alp = (const float*)d_in[13];
    const float* mix = (const float*)d_in[14];
    const float* bl  = (const float*)d_in[15];
    const float* Wo  = (const float*)d_in[16];
    const float* bo  = (const float*)d_in[17];
    const int* nsim  = (const int*)d_in[18];

    float* ws = (float*)d_ws;
    const size_t QKV = (size_t)BH_ * S_ * DH;   // 9,453,568
    float* qf = ws;
    float* kf = qf + QKV;
    float* vf = kf + QKV;
    float* om = vf + QKV;                        // BH_*S_
    float* zp = om + (size_t)BH_*S_;             // 2*BH_*S_
    float* yb = zp + (size_t)2*BH_*S_;           // B_*S_*DM
    float* outf = (float*)d_out;

    k_proj<<<BH_, 512, 0, stream>>>(x, Wq, bq, Wk, bk, Wv, bv, Wom, bom, Wth, bth,
                                    qf, kf, vf, om, zp);
    k_ode<<<BH_, 512, 0, stream>>>(qf, kf, om, mu, kap, alp, nsim, zp);
    k_attn<<<BH_*10, 512, 0, stream>>>(qf, kf, vf, zp, mix, bl, yb);
    dim3 gg(73, 8);
    k_gemm<<<gg, 256, 0, stream>>>(yb, Wo, bo, outf);
}

// Round 2
// 663.577 us; speedup vs baseline: 3.3357x; 3.3357x over previous
//
#include <hip/hip_runtime.h>
#include <hip/hip_bf16.h>

#define S_ 577
#define B_ 16
#define H_ 16
#define DH 64
#define DM 1024
#define BH_ 256
#define DT_ 0.01f
#define BETA_ 4.0f
#define SCALE_ 0.125f

typedef float f32x4 __attribute__((ext_vector_type(4)));
typedef short s16x8 __attribute__((ext_vector_type(8)));

__device__ inline short f2bf(float x) {
    unsigned b = __builtin_bit_cast(unsigned, x);
    b += 0x7fffu + ((b >> 16) & 1u);
    return (short)(b >> 16);
}

// ---------------------------------------------------------------------------
// K1: per-(b,h) projections: q,k,v = xh@W + b ; omega/theta ; z0 = (cos,sin)
// Writes q,k as f32 (for ODE) and q,k,v as bf16 (for attention).
// ---------------------------------------------------------------------------
__global__ __launch_bounds__(512) void k_proj(
    const float* __restrict__ x,
    const float* __restrict__ Wq, const float* __restrict__ bq,
    const float* __restrict__ Wk, const float* __restrict__ bk,
    const float* __restrict__ Wv, const float* __restrict__ bv,
    const float* __restrict__ Wom, const float* __restrict__ bom,
    const float* __restrict__ Wth, const float* __restrict__ bth,
    float* __restrict__ q, float* __restrict__ k,
    short* __restrict__ qh, short* __restrict__ kh, short* __restrict__ vh,
    float* __restrict__ om, float* __restrict__ zp)
{
    __shared__ __align__(16) float Wq_l[4096], Wk_l[4096], Wv_l[4096];
    __shared__ float Wom_l[64], Wth_l[64];
    int bh = blockIdx.x, b = bh >> 4, h = bh & 15;
    int tid = threadIdx.x;
    for (int i = tid; i < 4096; i += 512) {
        Wq_l[i] = Wq[(size_t)h*4096 + i];
        Wk_l[i] = Wk[(size_t)h*4096 + i];
        Wv_l[i] = Wv[(size_t)h*4096 + i];
    }
    if (tid < 64) { Wom_l[tid] = Wom[h*64 + tid]; Wth_l[tid] = Wth[h*64 + tid]; }
    __syncthreads();
    int wid = tid >> 6, lane = tid & 63;
    float bqv = bq[h*64 + lane], bkv = bk[h*64 + lane], bvv = bv[h*64 + lane];
    float bomv = bom[h], bthv = bth[h];
    for (int sb = wid*4; sb < S_; sb += 32) {
        float xr[4]; bool ok[4];
        #pragma unroll
        for (int r = 0; r < 4; ++r) {
            int s = sb + r; ok[r] = (s < S_);
            float xv = 0.f;
            if (ok[r]) xv = x[(size_t)b*S_*DM + (size_t)s*DM + h*DH + lane];
            if (!isfinite(xv)) xv = 0.f;
            xr[r] = xv;
        }
        float qa[4] = {0,0,0,0}, ka[4] = {0,0,0,0}, va[4] = {0,0,0,0};
        #pragma unroll 8
        for (int d = 0; d < 64; ++d) {
            float wq = Wq_l[d*64 + lane], wk = Wk_l[d*64 + lane], wv = Wv_l[d*64 + lane];
            #pragma unroll
            for (int r = 0; r < 4; ++r) {
                float xd = __shfl(xr[r], d, 64);
                qa[r] = fmaf(xd, wq, qa[r]);
                ka[r] = fmaf(xd, wk, ka[r]);
                va[r] = fmaf(xd, wv, va[r]);
            }
        }
        #pragma unroll
        for (int r = 0; r < 4; ++r) {
            float omp = xr[r] * Wom_l[lane], thp = xr[r] * Wth_l[lane];
            #pragma unroll
            for (int m = 32; m; m >>= 1) {
                omp += __shfl_xor(omp, m, 64);
                thp += __shfl_xor(thp, m, 64);
            }
            if (ok[r]) {
                int s = sb + r;
                size_t base = (size_t)bh*S_*DH + (size_t)s*DH + lane;
                float qv = qa[r] + bqv, kv2 = ka[r] + bkv, vv2 = va[r] + bvv;
                q[base] = qv; k[base] = kv2;
                qh[base] = f2bf(qv); kh[base] = f2bf(kv2); vh[base] = f2bf(vv2);
                if (lane == 0) {
                    float oms = omp + bomv, th = thp + bthv;
                    om[(size_t)bh*S_ + s] = oms;
                    float si, co;
                    sincosf(th, &si, &co);
                    reinterpret_cast<float2*>(zp)[(size_t)bh*S_ + s] = make_float2(co, si);
                }
            }
        }
    }
}

// ---------------------------------------------------------------------------
// K2: Stuart-Landau ODE, 10 Heun steps. Kc@z factored as c*q@(k^T z). fp32.
// ---------------------------------------------------------------------------
__global__ __launch_bounds__(512) void k_ode(
    const float* __restrict__ q, const float* __restrict__ k,
    const float* __restrict__ om,
    const float* __restrict__ mu, const float* __restrict__ kappa,
    const float* __restrict__ alpha, const int* __restrict__ nsim,
    float* __restrict__ zp)
{
    __shared__ __align__(16) float k_l[S_*DH];
    __shared__ float2 z_l[S_], z1_l[S_];
    __shared__ float2 kz_s[8][64];
    int bh = blockIdx.x, h = bh & 15;
    int tid = threadIdx.x;
    const float* kg = k + (size_t)bh*S_*DH;
    {
        const float4* kg4 = reinterpret_cast<const float4*>(kg);
        float4* kl4 = reinterpret_cast<float4*>(k_l);
        for (int i = tid; i < S_*DH/4; i += 512) kl4[i] = kg4[i];
    }
    float2* zpg = reinterpret_cast<float2*>(zp) + (size_t)bh*S_;
    for (int i = tid; i < S_; i += 512) z_l[i] = zpg[i];
    float ca = cosf(alpha[h]), sa = sinf(alpha[h]);
    float muv = mu[h];
    float cc = kappa[h] * SCALE_ / (float)S_;
    int NT = nsim[0];
    __syncthreads();
    int wid = tid >> 6, lane = tid & 63;
    int s0 = wid * 73, s1 = min(S_, s0 + 73);
    int i8 = lane >> 3, d0 = (lane & 7) << 3;
    const float* qg = q + (size_t)bh*S_*DH;
    const float* omg = om + (size_t)bh*S_;
    for (int ev = 0; ev < 2*NT; ++ev) {
        bool second = ev & 1;
        const float2* zin = second ? z1_l : z_l;
        float accr = 0.f, acci = 0.f;
        for (int s = s0; s < s1; ++s) {
            float kv = k_l[s*64 + lane];
            float2 z = zin[s];
            accr = fmaf(kv, z.x, accr);
            acci = fmaf(kv, z.y, acci);
        }
        kz_s[wid][lane] = make_float2(accr, acci);
        __syncthreads();
        if (tid < 64) {
            float2 t = kz_s[0][lane];
            #pragma unroll
            for (int w = 1; w < 8; ++w) { float2 u = kz_s[w][lane]; t.x += u.x; t.y += u.y; }
            kz_s[0][lane] = t;
        }
        __syncthreads();
        float kzr[8], kzi[8];
        #pragma unroll
        for (int j = 0; j < 8; ++j) { float2 t = kz_s[0][d0 + j]; kzr[j] = t.x; kzi[j] = t.y; }
        for (int sb = s0; sb < s1; sb += 8) {
            int s = sb + i8;
            bool act = (s < s1);
            float ur = 0.f, ui = 0.f;
            if (act) {
                const float4* q4 = reinterpret_cast<const float4*>(qg + (size_t)s*DH + d0);
                float4 qa = q4[0], qb = q4[1];
                ur = fmaf(qa.x,kzr[0],fmaf(qa.y,kzr[1],fmaf(qa.z,kzr[2],fmaf(qa.w,kzr[3],
                     fmaf(qb.x,kzr[4],fmaf(qb.y,kzr[5],fmaf(qb.z,kzr[6],qb.w*kzr[7])))))));
                ui = fmaf(qa.x,kzi[0],fmaf(qa.y,kzi[1],fmaf(qa.z,kzi[2],fmaf(qa.w,kzi[3],
                     fmaf(qb.x,kzi[4],fmaf(qb.y,kzi[5],fmaf(qb.z,kzi[6],qb.w*kzi[7])))))));
            }
            #pragma unroll
            for (int m = 1; m < 8; m <<= 1) {
                ur += __shfl_xor(ur, m, 64);
                ui += __shfl_xor(ui, m, 64);
            }
            if (act) {
                float2 z = zin[s];
                float omega_s = omg[s];
                float urc = cc*ur, uic = cc*ui;
                float cr = ca*urc + sa*uic;
                float ci = ca*uic - sa*urc;
                float g = muv - (z.x*z.x + z.y*z.y);
                float dr = fmaf(g, z.x, fmaf(-omega_s, z.y, cr));
                float di = fmaf(g, z.y, fmaf( omega_s, z.x, ci));
                if (d0 == 0) {
                    float2 zb = z_l[s];
                    if (!second) {
                        z1_l[s] = make_float2(fmaf(DT_, dr, z.x), fmaf(DT_, di, z.y));
                        z_l[s]  = make_float2(fmaf(0.5f*DT_, dr, zb.x), fmaf(0.5f*DT_, di, zb.y));
                    } else {
                        z_l[s]  = make_float2(fmaf(0.5f*DT_, dr, zb.x), fmaf(0.5f*DT_, di, zb.y));
                    }
                }
            }
        }
        __syncthreads();
    }
    for (int i = tid; i < S_; i += 512) zpg[i] = z_l[i];
}

// ---------------------------------------------------------------------------
// K3: dual flash attention, MFMA 16x16x32 bf16.
// Block: 8 waves x 16 q-rows = 128 rows; 5 blocks per (b,h); 10 k/v tiles.
// Fragment pattern (m92-verified): operand row = lane&15, k-chunk (lane>>4)*8;
// D: row = 4*(lane>>4)+reg, col = lane&15. LDS rows XOR-swizzled (^(row&7)<<3).
// ---------------------------------------------------------------------------
__global__ __launch_bounds__(512) void k_attn(
    const short* __restrict__ qh, const short* __restrict__ kh,
    const short* __restrict__ vh, const float* __restrict__ zp,
    const float* __restrict__ mix_logit, const float* __restrict__ band_logits,
    short* __restrict__ yh)
{
    __shared__ short q_l[128*64];     // 16 KB
    __shared__ short k_l2[64*64];     // 8 KB
    __shared__ short vT_l[64*64];     // 8 KB (transposed: [d][t])
    __shared__ short P_l[8][2][1024]; // 32 KB: per-wave [branch][16s x 64t]
    __shared__ float2 zs_l[128];
    __shared__ float2 zt_l[64];

    int blk = blockIdx.x;
    int bh = blk / 5, rc = blk - bh*5;
    int b = bh >> 4, h = bh & 15;
    int r0 = rc * 128;
    int tid = threadIdx.x, w = tid >> 6, lane = tid & 63;
    int c = lane & 15, g = lane >> 4;

    const short* qg = qh + (size_t)bh*S_*DH;
    const short* kg = kh + (size_t)bh*S_*DH;
    const short* vg = vh + (size_t)bh*S_*DH;
    const float2* zpg = (const float2*)zp + (size_t)bh*S_;

    // stage q rows (zero-padded) + z_s (pre-scaled by BETA)
    #pragma unroll
    for (int i = 0; i < 2; ++i) {
        int cid = tid + 512*i;
        int row = cid >> 3, ch = cid & 7;
        int s = r0 + row;
        s16x8 val = {0,0,0,0,0,0,0,0};
        if (s < S_) val = *(const s16x8*)(qg + (size_t)s*DH + ch*8);
        *(s16x8*)&q_l[row*64 + ((ch*8) ^ ((row&7)<<3))] = val;
    }
    if (tid < 128) {
        float2 z = (r0 + tid < S_) ? zpg[r0 + tid] : make_float2(0.f,0.f);
        zs_l[tid] = make_float2(z.x*BETA_, z.y*BETA_);
    }
    __syncthreads();

    // hoisted per-wave q A-fragments (K halves 0..31, 32..63)
    s16x8 qf0, qf1;
    {
        int row = w*16 + c;
        qf0 = *(const s16x8*)&q_l[row*64 + ((g*8)      ^ ((row&7)<<3))];
        qf1 = *(const s16x8*)&q_l[row*64 + ((g*8 + 32) ^ ((row&7)<<3))];
    }

    f32x4 accv[4], accr[4];
    float m_v[4], m_r[4], Z_v[4], Z_r[4];
    #pragma unroll
    for (int i = 0; i < 4; ++i) {
        accv[i] = (f32x4){0.f,0.f,0.f,0.f};
        accr[i] = (f32x4){0.f,0.f,0.f,0.f};
        m_v[i] = -1e30f; m_r[i] = -1e30f; Z_v[i] = 0.f; Z_r[i] = 0.f;
    }

    for (int tt = 0; tt < 10; ++tt) {
        int t0g = tt * 64;
        __syncthreads();
        {   // stage k tile (row-major, swizzled)
            int row = tid >> 3, ch = tid & 7;
            int t = t0g + row;
            s16x8 val = {0,0,0,0,0,0,0,0};
            if (t < S_) val = *(const s16x8*)(kg + (size_t)t*DH + ch*8);
            *(s16x8*)&k_l2[row*64 + ((ch*8) ^ ((row&7)<<3))] = val;
        }
        {   // stage v transposed: vT[d][t], swizzled per d-row
            int t = tid >> 3, d0 = (tid & 7) << 3;
            s16x8 vv = {0,0,0,0,0,0,0,0};
            if (t0g + t < S_) vv = *(const s16x8*)(vg + (size_t)(t0g+t)*DH + d0);
            #pragma unroll
            for (int j = 0; j < 8; ++j)
                vT_l[(d0+j)*64 + (t ^ (((d0+j)&7)<<3))] = vv[j];
        }
        if (tid < 64) zt_l[tid] = (t0g + tid < S_) ? zpg[t0g + tid] : make_float2(0.f,0.f);
        __syncthreads();

        // ---- QK^T: 4 t-subtiles x 2 K-halves
        f32x4 sv[4];
        #pragma unroll
        for (int sub = 0; sub < 4; ++sub) {
            int row = sub*16 + c;
            s16x8 kf0 = *(const s16x8*)&k_l2[row*64 + ((g*8)      ^ ((c&7)<<3))];
            s16x8 kf1 = *(const s16x8*)&k_l2[row*64 + ((g*8 + 32) ^ ((c&7)<<3))];
            f32x4 a = {0.f,0.f,0.f,0.f};
            a = __builtin_amdgcn_mfma_f32_16x16x32_bf16(qf0, kf0, a, 0, 0, 0);
            a = __builtin_amdgcn_mfma_f32_16x16x32_bf16(qf1, kf1, a, 0, 0, 0);
            sv[sub] = a * SCALE_;
        }
        float2 zt_s[4];
        #pragma unroll
        for (int sub = 0; sub < 4; ++sub) zt_s[sub] = zt_l[sub*16 + c];

        bool mask = (t0g + 63 >= S_);
        // ---- dual online softmax (per D-row r; t spread over lane&15 x subs)
        #pragma unroll
        for (int r = 0; r < 4; ++r) {
            int srow = w*16 + (g<<2) + r;        // block-local s
            float2 zs = zs_l[srow];
            float sv_r[4], sr_r[4];
            #pragma unroll
            for (int sub = 0; sub < 4; ++sub) {
                float a = sv[sub][r];
                float rr = fmaf(zs.x, zt_s[sub].x, zs.y * zt_s[sub].y);
                bool bad = mask && ((t0g + sub*16 + c) >= S_);
                sv_r[sub] = bad ? -1e30f : a;
                sr_r[sub] = bad ? -1e30f : rr;
            }
            float mlv = fmaxf(fmaxf(sv_r[0],sv_r[1]), fmaxf(sv_r[2],sv_r[3]));
            float mlr = fmaxf(fmaxf(sr_r[0],sr_r[1]), fmaxf(sr_r[2],sr_r[3]));
            #pragma unroll
            for (int mm = 1; mm < 16; mm <<= 1) {
                mlv = fmaxf(mlv, __shfl_xor(mlv, mm, 64));
                mlr = fmaxf(mlr, __shfl_xor(mlr, mm, 64));
            }
            float nmv = fmaxf(m_v[r], mlv), nmr = fmaxf(m_r[r], mlr);
            float fv = __expf(m_v[r] - nmv), fr = __expf(m_r[r] - nmr);
            m_v[r] = nmv; m_r[r] = nmr;
            int sl = (g<<2) + r;                 // wave-local s (P row)
            float sumv = 0.f, sumr = 0.f;
            #pragma unroll
            for (int sub = 0; sub < 4; ++sub) {
                float pv = __expf(sv_r[sub] - nmv);
                float pr = __expf(sr_r[sub] - nmr);
                sumv += pv; sumr += pr;
                int t = sub*16 + c;
                P_l[w][0][sl*64 + (t ^ ((sl&7)<<3))] = f2bf(pv);
                P_l[w][1][sl*64 + (t ^ ((sl&7)<<3))] = f2bf(pr);
            }
            #pragma unroll
            for (int mm = 1; mm < 16; mm <<= 1) {
                sumv += __shfl_xor(sumv, mm, 64);
                sumr += __shfl_xor(sumr, mm, 64);
            }
            Z_v[r] = fmaf(Z_v[r], fv, sumv);
            Z_r[r] = fmaf(Z_r[r], fr, sumr);
            #pragma unroll
            for (int d = 0; d < 4; ++d) { accv[d][r] *= fv; accr[d][r] *= fr; }
        }

        // ---- PV: A = P (wave-local LDS), B = vT; 4 d-subtiles x 2 K-halves
        #pragma unroll
        for (int hh = 0; hh < 2; ++hh) {
            int kc = g*8 + 32*hh;
            s16x8 pa_v = *(const s16x8*)&P_l[w][0][c*64 + (kc ^ ((c&7)<<3))];
            s16x8 pa_r = *(const s16x8*)&P_l[w][1][c*64 + (kc ^ ((c&7)<<3))];
            #pragma unroll
            for (int d = 0; d < 4; ++d) {
                int row = d*16 + c;
                s16x8 vf = *(const s16x8*)&vT_l[row*64 + (kc ^ ((c&7)<<3))];
                accv[d] = __builtin_amdgcn_mfma_f32_16x16x32_bf16(pa_v, vf, accv[d], 0, 0, 0);
                accr[d] = __builtin_amdgcn_mfma_f32_16x16x32_bf16(pa_r, vf, accr[d], 0, 0, 0);
            }
        }
    }

    // ---- epilogue: y = mix*gate*(yr/Zr) + (1-mix)*(yv/Zv), write bf16
    float mixv = 1.f/(1.f + __expf(-mix_logit[h]));
    #pragma unroll
    for (int d = 0; d < 4; ++d) {
        float gate = 1.f/(1.f + __expf(-band_logits[h*4 + d]));
        #pragma unroll
        for (int r = 0; r < 4; ++r) {
            int s = r0 + w*16 + (g<<2) + r;
            if (s < S_) {
                float val = mixv*gate*(accr[d][r]/Z_r[r]) + (1.f-mixv)*(accv[d][r]/Z_v[r]);
                yh[(size_t)b*S_*DM + (size_t)s*DM + h*DH + d*16 + c] = f2bf(val);
            }
        }
    }
}

// ---------------------------------------------------------------------------
// K4b: Wo (f32 [k][n]) -> WoT (bf16 [n][k]) tile transpose
// ---------------------------------------------------------------------------
__global__ __launch_bounds__(256) void k_cvt(
    const float* __restrict__ Wo, short* __restrict__ Bt)
{
    __shared__ short tl[64][65];
    int k0 = blockIdx.x * 64, n0 = blockIdx.y * 64;
    int tid = threadIdx.x;
    int r = tid >> 2, cb = (tid & 3) * 16;
    #pragma unroll
    for (int j4 = 0; j4 < 4; ++j4) {
        float4 v = *reinterpret_cast<const float4*>(Wo + (size_t)(k0+r)*1024 + n0 + cb + j4*4);
        tl[r][cb + j4*4 + 0] = f2bf(v.x);
        tl[r][cb + j4*4 + 1] = f2bf(v.y);
        tl[r][cb + j4*4 + 2] = f2bf(v.z);
        tl[r][cb + j4*4 + 3] = f2bf(v.w);
    }
    __syncthreads();
    s16x8 v0, v1;
    #pragma unroll
    for (int j = 0; j < 8; ++j) { v0[j] = tl[cb+j][r]; v1[j] = tl[cb+8+j][r]; }
    *(s16x8*)(Bt + (size_t)(n0+r)*1024 + k0 + cb)     = v0;
    *(s16x8*)(Bt + (size_t)(n0+r)*1024 + k0 + cb + 8) = v1;
}

// ---------------------------------------------------------------------------
// K4: out = y(9232x1024 bf16) @ Wo + bo, MFMA 16x16x32 bf16, 128x128 tile.
// ---------------------------------------------------------------------------
__global__ __launch_bounds__(256) void k_gemm(
    const short* __restrict__ A, const short* __restrict__ Bt,
    const float* __restrict__ bias, float* __restrict__ out)
{
    const int M = B_ * S_;   // 9232
    __shared__ short A_l[128*64];
    __shared__ short B_l[128*64];
    int m0 = blockIdx.x * 128, n0 = blockIdx.y * 128;
    int tid = threadIdx.x, w = tid >> 6, lane = tid & 63;
    int c = lane & 15, g = lane >> 4;
    int mb = (w & 1) * 64, nb = (w >> 1) * 64;
    f32x4 acc[4][4];
    #pragma unroll
    for (int i = 0; i < 4; ++i)
        #pragma unroll
        for (int j = 0; j < 4; ++j) acc[i][j] = (f32x4){0.f,0.f,0.f,0.f};
    for (int k0 = 0; k0 < 1024; k0 += 64) {
        __syncthreads();
        #pragma unroll
        for (int i = 0; i < 4; ++i) {
            int cid = tid + 256*i;
            int row = cid >> 3, ch = cid & 7;
            int m = m0 + row;
            s16x8 av = {0,0,0,0,0,0,0,0};
            if (m < M) av = *(const s16x8*)(A + (size_t)m*1024 + k0 + ch*8);
            *(s16x8*)&A_l[row*64 + ((ch*8) ^ ((row&7)<<3))] = av;
            s16x8 bv = *(const s16x8*)(Bt + (size_t)(n0+row)*1024 + k0 + ch*8);
            *(s16x8*)&B_l[row*64 + ((ch*8) ^ ((row&7)<<3))] = bv;
        }
        __syncthreads();
        s16x8 af[4][2], bf[4][2];
        #pragma unroll
        for (int i = 0; i < 4; ++i) {
            int ra = mb + i*16 + c;
            af[i][0] = *(const s16x8*)&A_l[ra*64 + ((g*8)      ^ ((c&7)<<3))];
            af[i][1] = *(const s16x8*)&A_l[ra*64 + ((g*8 + 32) ^ ((c&7)<<3))];
            int rb = nb + i*16 + c;
            bf[i][0] = *(const s16x8*)&B_l[rb*64 + ((g*8)      ^ ((c&7)<<3))];
            bf[i][1] = *(const s16x8*)&B_l[rb*64 + ((g*8 + 32) ^ ((c&7)<<3))];
        }
        #pragma unroll
        for (int i = 0; i < 4; ++i)
            #pragma unroll
            for (int j = 0; j < 4; ++j) {
                acc[i][j] = __builtin_amdgcn_mfma_f32_16x16x32_bf16(af[i][0], bf[j][0], acc[i][j], 0, 0, 0);
                acc[i][j] = __builtin_amdgcn_mfma_f32_16x16x32_bf16(af[i][1], bf[j][1], acc[i][j], 0, 0, 0);
            }
    }
    #pragma unroll
    for (int j = 0; j < 4; ++j) {
        float bv = bias[n0 + nb + j*16 + c];
        #pragma unroll
        for (int i = 0; i < 4; ++i)
            #pragma unroll
            for (int r = 0; r < 4; ++r) {
                int m = m0 + mb + i*16 + 4*g + r;
                if (m < M) out[(size_t)m*1024 + n0 + nb + j*16 + c] = acc[i][j][r] + bv;
            }
    }
}

// ---------------------------------------------------------------------------
extern "C" void kernel_launch(void* const* d_in, const int* in_sizes, int n_in,
                              void* d_out, int out_size, void* d_ws, size_t ws_size,
                              hipStream_t stream)
{
    const float* x   = (const float*)d_in[0];
    const float* Wq  = (const float*)d_in[1];
    const float* bq  = (const float*)d_in[2];
    const float* Wk  = (const float*)d_in[3];
    const float* bk  = (const float*)d_in[4];
    const float* Wv  = (const float*)d_in[5];
    const float* bv  = (const float*)d_in[6];
    const float* Wom = (const float*)d_in[7];
    const float* bom = (const float*)d_in[8];
    const float* Wth = (const float*)d_in[9];
    const float* bth = (const float*)d_in[10];
    const float* mu  = (const float*)d_in[11];
    const float* kap = (const float*)d_in[12];
    const float* alp = (const float*)d_in[13];
    const float* mix = (const float*)d_in[14];
    const float* bl  = (const float*)d_in[15];
    const float* Wo  = (const float*)d_in[16];
    const float* bo  = (const float*)d_in[17];
    const int* nsim  = (const int*)d_in[18];

    float* ws = (float*)d_ws;
    const size_t QKV = (size_t)BH_ * S_ * DH;    // 9,453,568
    float* qf = ws;                               // f32 q (ODE only)
    float* kf = qf + QKV;                         // f32 k (ODE only)
    float* om = kf + QKV;                         // BH*S
    float* zp = om + (size_t)BH_*S_;              // 2*BH*S
    short* qh = (short*)(zp + (size_t)2*BH_*S_);  // bf16 q
    short* kh = qh + QKV;                         // bf16 k
    short* vh = kh + QKV;                         // bf16 v
    // aliases (safe by stream ordering: qf/kf dead after k_ode):
    short* yh  = (short*)qf;                      // bf16 y (attn out)
    short* WoT = (short*)kf;                      // bf16 Wo^T
    float* outf = (float*)d_out;

    k_proj<<<BH_, 512, 0, stream>>>(x, Wq, bq, Wk, bk, Wv, bv, Wom, bom, Wth, bth,
                                    qf, kf, qh, kh, vh, om, zp);
    k_ode<<<BH_, 512, 0, stream>>>(qf, kf, om, mu, kap, alp, nsim, zp);
    k_cvt<<<dim3(16,16), 256, 0, stream>>>(Wo, WoT);
    k_attn<<<BH_*5, 512, 0, stream>>>(qh, kh, vh, zp, mix, bl, yh);
    dim3 gg(73, 8);
    k_gemm<<<gg, 256, 0, stream>>>(yh, WoT, bo, outf);
}